// Round 3
// baseline (235.401 us; speedup 1.0000x reference)
//
#include <hip/hip_runtime.h>
#include <hip/hip_bf16.h>

// Shapes (fixed by the reference)
#define BB 16
#define HH 64
#define WW 64
#define CC 256
#define OH 128
#define OW 128
#define FF 256

typedef __attribute__((ext_vector_type(8))) short bf16x8;
typedef __attribute__((ext_vector_type(4))) float f32x4;

// RNE float -> bf16 bits
__device__ __forceinline__ short f2bf(float x) {
    union { float f; unsigned u; } v; v.f = x;
    unsigned r = v.u + 0x7fffu + ((v.u >> 16) & 1u);
    return (short)(r >> 16);
}

// prep: blocks 0..255 transpose pw [c][f] f32 -> pwt [f][c] bf16;
//       block 256 repacks dw [(r*4+s)*256+c] -> dwb [(r*256+c)*4+s] (f32)
__global__ void prep_kernel(const float* __restrict__ pw, const float* __restrict__ dw,
                            short* __restrict__ pwt, float* __restrict__ dwb) {
    if (blockIdx.x < 256) {
        int f = blockIdx.x, c = threadIdx.x;
        pwt[f * CC + c] = f2bf(pw[c * FF + f]);
    } else {
        for (int k = threadIdx.x; k < 4 * 4 * CC; k += 256) {
            int r = k >> 10;
            int rem = k & 1023;
            int s = rem >> 8;
            int c = rem & 255;
            dwb[(r * CC + c) * 4 + s] = dw[(r * 4 + s) * CC + c];
        }
    }
}

__device__ __forceinline__ void tap(float acc[8], const float w[8], const float* xptr) {
    const float4* xp = reinterpret_cast<const float4*>(xptr);
    float4 x0 = xp[0], x1 = xp[1];
    acc[0] += w[0] * x0.x; acc[1] += w[1] * x0.y;
    acc[2] += w[2] * x0.z; acc[3] += w[3] * x0.w;
    acc[4] += w[4] * x1.x; acc[5] += w[5] * x1.y;
    acc[6] += w[6] * x1.z; acc[7] += w[7] * x1.w;
}

// One block = (b, oh, quarter-of-ow): 32 output cols x 256 f. 256 threads, 4 waves.
__global__ __launch_bounds__(256, 5)
void sepconvt_kernel(const float* __restrict__ X,
                     const float* __restrict__ dwb,
                     const short* __restrict__ pwt,
                     const float* __restrict__ bias,
                     float* __restrict__ out) {
    __shared__ bf16x8 t_lds[32 * 32];   // 16 KiB: depthwise result (bf16), swizzled

    const int tid = threadIdx.x;
    const int blk = blockIdx.x;         // ((b*OH)+oh)*4 + qw
    const int qw = blk & 3;
    const int oh = (blk >> 2) & (OH - 1);
    const int b  = blk >> 9;

    // Row taps: even oh -> (r=1, i=oh/2), (r=3, i=oh/2-1); odd -> (r=0,(oh+1)/2),(r=2,(oh-1)/2)
    int r0, r1, i0, i1;
    if (oh & 1) { r0 = 0; i0 = (oh + 1) >> 1; r1 = 2; i1 = (oh - 1) >> 1; }
    else        { r0 = 1; i0 = oh >> 1;       r1 = 3; i1 = (oh >> 1) - 1; }

    // ---- Phase 1: depthwise transposed conv -> t_lds (bf16) ----
    {
        const int cg  = tid & 31;        // 8-channel group
        const int c0  = cg << 3;
        const int owp = tid >> 5;        // 0..7; ow parity fixed (stride 8)
        const int par = owp & 1;

        // Weights: dwb[(r*256+c)*4 + s] -> float4 of s=0..3 for (r,c).
        // even ow uses s={1,3}; odd ow uses s={0,2}.
        float w[2][2][8];
        const float4* dwb4 = reinterpret_cast<const float4*>(dwb);
        #pragma unroll
        for (int e = 0; e < 8; ++e) {
            float4 wa = dwb4[r0 * CC + c0 + e];
            float4 wb = dwb4[r1 * CC + c0 + e];
            w[0][0][e] = par ? wa.x : wa.y;   // s = se
            w[0][1][e] = par ? wa.z : wa.w;   // s = so
            w[1][0][e] = par ? wb.x : wb.y;
            w[1][1][e] = par ? wb.z : wb.w;
        }

        const bool va0 = (unsigned)i0 < HH;
        const bool va1 = (unsigned)i1 < HH;
        const float* Xr0 = X + (size_t)(b * HH + (va0 ? i0 : 0)) * WW * CC;
        const float* Xr1 = X + (size_t)(b * HH + (va1 ? i1 : 0)) * WW * CC;

        #pragma unroll
        for (int t = 0; t < 4; ++t) {
            const int owl = owp + t * 8;        // local 0..31
            const int ow  = qw * 32 + owl;      // global output col
            int je, jo;
            if (par) { je = (ow + 1) >> 1; jo = (ow - 1) >> 1; }
            else     { je = ow >> 1;       jo = (ow >> 1) - 1; }
            const bool vje = (unsigned)je < WW;
            const bool vjo = (unsigned)jo < WW;

            float acc[8];
            #pragma unroll
            for (int e = 0; e < 8; ++e) acc[e] = 0.f;

            if (va0) {
                if (vje) tap(acc, w[0][0], Xr0 + je * CC + c0);
                if (vjo) tap(acc, w[0][1], Xr0 + jo * CC + c0);
            }
            if (va1) {
                if (vje) tap(acc, w[1][0], Xr1 + je * CC + c0);
                if (vjo) tap(acc, w[1][1], Xr1 + jo * CC + c0);
            }

            bf16x8 tv;
            #pragma unroll
            for (int e = 0; e < 8; ++e) tv[e] = f2bf(acc[e]);
            t_lds[owl * 32 + (cg ^ (owl & 7))] = tv;
        }
    }
    __syncthreads();

    // ---- Phase 2: pointwise GEMM via MFMA, swapped operands ----
    // D = pw_frag (A, rows=f) * t_frag (B, cols=ow): D[f][ow]
    const int lane = tid & 63;
    const int wid  = tid >> 6;        // 4 waves, each owns 64 f columns
    const int lr   = lane & 15;
    const int lk8  = lane >> 4;       // k-subgroup 0..3
    const bf16x8* pwt_v = reinterpret_cast<const bf16x8*>(pwt);

    f32x4 acc[2][4];                  // [mi(ow-tile)][ni(f-tile)]
    #pragma unroll
    for (int mi = 0; mi < 2; ++mi)
        #pragma unroll
        for (int ni = 0; ni < 4; ++ni)
            acc[mi][ni] = (f32x4){0.f, 0.f, 0.f, 0.f};

    #pragma unroll
    for (int kk = 0; kk < 8; ++kk) {            // K = 256, 32 per mfma
        const int kg = kk * 4 + lk8;            // 16B group index along K
        bf16x8 af[2], bfr[4];
        #pragma unroll
        for (int mi = 0; mi < 2; ++mi) {
            const int owl = mi * 16 + lr;
            af[mi] = t_lds[owl * 32 + (kg ^ (owl & 7))];
        }
        #pragma unroll
        for (int ni = 0; ni < 4; ++ni)
            bfr[ni] = pwt_v[(wid * 64 + ni * 16 + lr) * 32 + kg];
        #pragma unroll
        for (int mi = 0; mi < 2; ++mi)
            #pragma unroll
            for (int ni = 0; ni < 4; ++ni)
                acc[mi][ni] = __builtin_amdgcn_mfma_f32_16x16x32_bf16(
                    bfr[ni], af[mi], acc[mi][ni], 0, 0, 0);
    }

    // ---- Epilogue: bias + relu + vectorized store ----
    // D[f][ow]: f = wid*64 + ni*16 + (lane>>4)*4 + q, ow = qw*32 + mi*16 + (lane&15)
    float* obase = out + ((size_t)(b * OH + oh) * OW + qw * 32) * FF;
    const int fq = lk8 * 4;
    #pragma unroll
    for (int ni = 0; ni < 4; ++ni) {
        const int f0 = wid * 64 + ni * 16 + fq;
        const float4 bv = *reinterpret_cast<const float4*>(&bias[f0]);
        #pragma unroll
        for (int mi = 0; mi < 2; ++mi) {
            const int ow = mi * 16 + lr;
            float4 v;
            v.x = acc[mi][ni][0] + bv.x;
            v.y = acc[mi][ni][1] + bv.y;
            v.z = acc[mi][ni][2] + bv.z;
            v.w = acc[mi][ni][3] + bv.w;
            v.x = v.x > 0.f ? v.x : 0.f;
            v.y = v.y > 0.f ? v.y : 0.f;
            v.z = v.z > 0.f ? v.z : 0.f;
            v.w = v.w > 0.f ? v.w : 0.f;
            *reinterpret_cast<float4*>(&obase[(size_t)ow * FF + f0]) = v;
        }
    }
}

extern "C" void kernel_launch(void* const* d_in, const int* in_sizes, int n_in,
                              void* d_out, int out_size, void* d_ws, size_t ws_size,
                              hipStream_t stream) {
    (void)in_sizes; (void)n_in; (void)out_size; (void)ws_size;
    const float* X    = (const float*)d_in[0];
    const float* dw   = (const float*)d_in[1];
    const float* pw   = (const float*)d_in[2];
    const float* bias = (const float*)d_in[3];
    float* out = (float*)d_out;
    short* pwt = (short*)d_ws;                        // 256*256*2 = 128 KiB
    float* dwb = (float*)((char*)d_ws + 131072);      // 4*256*4*4 = 16 KiB

    prep_kernel<<<dim3(257), dim3(256), 0, stream>>>(pw, dw, pwt, dwb);
    sepconvt_kernel<<<dim3(BB * OH * 4), dim3(256), 0, stream>>>(X, dwb, pwt, bias, out);
}

// Round 5
// 231.668 us; speedup vs baseline: 1.0161x; 1.0161x over previous
//
#include <hip/hip_runtime.h>
#include <hip/hip_bf16.h>

// Shapes (fixed by the reference)
#define BB 16
#define HH 64
#define WW 64
#define CC 256
#define OH 128
#define OW 128
#define FF 256
#define TPB 8           // half-row tiles per block

typedef __attribute__((ext_vector_type(8))) short bf16x8;
typedef __attribute__((ext_vector_type(4))) float f32x4;

// RNE float -> bf16 bits (prep kernel only)
__device__ __forceinline__ short f2bf(float x) {
    union { float f; unsigned u; } v; v.f = x;
    unsigned r = v.u + 0x7fffu + ((v.u >> 16) & 1u);
    return (short)(r >> 16);
}

// packed f32x2 -> bf16x2 (1 VALU instr)
__device__ __forceinline__ unsigned cvtpk(float lo, float hi) {
    unsigned r;
    asm("v_cvt_pk_bf16_f32 %0, %1, %2" : "=v"(r) : "v"(lo), "v"(hi));
    return r;
}

// prep: blocks 0..255 transpose pw [c][f] f32 -> pwt [f][c] bf16;
//       block 256 repacks dw [(r*4+s)*256+c] -> dwb [(r*256+c)*4+s] (f32)
__global__ void prep_kernel(const float* __restrict__ pw, const float* __restrict__ dw,
                            short* __restrict__ pwt, float* __restrict__ dwb) {
    if (blockIdx.x < 256) {
        int f = blockIdx.x, c = threadIdx.x;
        pwt[f * CC + c] = f2bf(pw[c * FF + f]);
    } else {
        for (int k = threadIdx.x; k < 4 * 4 * CC; k += 256) {
            int r = k >> 10;
            int rem = k & 1023;
            int s = rem >> 8;
            int c = rem & 255;
            dwb[(r * CC + c) * 4 + s] = dw[(r * 4 + s) * CC + c];
        }
    }
}

__device__ __forceinline__ void tap(float acc[8], const float w[8], const float* xptr) {
    const float4* xp = reinterpret_cast<const float4*>(xptr);
    float4 x0 = xp[0], x1 = xp[1];
    acc[0] += w[0] * x0.x; acc[1] += w[1] * x0.y;
    acc[2] += w[2] * x0.z; acc[3] += w[3] * x0.w;
    acc[4] += w[4] * x1.x; acc[5] += w[5] * x1.y;
    acc[6] += w[6] * x1.z; acc[7] += w[7] * x1.w;
}

// 512 threads: waves 0-3 produce depthwise tiles (64 ow x 256 c, bf16, swizzled LDS),
// waves 4-7 consume them with MFMA pointwise GEMM + nt stores. Double-buffered.
__global__ __launch_bounds__(512, 4)
void sepconvt_kernel(const float* __restrict__ X,
                     const float* __restrict__ dwb,
                     const short* __restrict__ pwt,
                     const float* __restrict__ bias,
                     float* __restrict__ out) {
    __shared__ bf16x8 tbuf[2][64 * 32];   // 2 x 32 KiB

    const int tid = threadIdx.x;
    const int wid = tid >> 6;
    const bool producer = (wid < 4);
    const int g0 = blockIdx.x * TPB;      // first half-row tile of this block

    // ---------------- producer state ----------------
    const int cg  = tid & 31;             // 8-channel group (producers: tid 0..255)
    const int c0  = cg << 3;
    const int owp = (tid >> 5) & 7;       // 0..7, ow stride 8
    const int par = owp & 1;
    const float4* dwb4 = reinterpret_cast<const float4*>(dwb);

    // ---------------- consumer state ----------------
    const int lane = tid & 63;
    const int cw   = wid - 4;             // consumer wave 0..3 -> f block
    const int lr   = lane & 15;
    const int lk8  = lane >> 4;           // 0..3
    const bf16x8* pwt_v = reinterpret_cast<const bf16x8*>(pwt);

    f32x4 bv[4];
    if (!producer) {
        #pragma unroll
        for (int ni = 0; ni < 4; ++ni)
            bv[ni] = *reinterpret_cast<const f32x4*>(&bias[cw * 64 + ni * 16 + lk8 * 4]);
    }

    // produce tile g into tbuf[pb]
    auto produce = [&](int g, int pb) {
        const int hw = g & 1;
        const int oh = (g >> 1) & (OH - 1);
        const int b  = g >> 8;
        int r0, r1, i0, i1;
        if (oh & 1) { r0 = 0; i0 = (oh + 1) >> 1; r1 = 2; i1 = (oh - 1) >> 1; }
        else        { r0 = 1; i0 = oh >> 1;       r1 = 3; i1 = (oh >> 1) - 1; }

        float w[2][2][8];
        #pragma unroll
        for (int e = 0; e < 8; ++e) {
            float4 wa = dwb4[r0 * CC + c0 + e];
            float4 wb = dwb4[r1 * CC + c0 + e];
            w[0][0][e] = par ? wa.x : wa.y;
            w[0][1][e] = par ? wa.z : wa.w;
            w[1][0][e] = par ? wb.x : wb.y;
            w[1][1][e] = par ? wb.z : wb.w;
        }

        const bool va0 = (unsigned)i0 < HH;
        const bool va1 = (unsigned)i1 < HH;
        const float* Xr0 = X + (size_t)(b * HH + (va0 ? i0 : 0)) * WW * CC;
        const float* Xr1 = X + (size_t)(b * HH + (va1 ? i1 : 0)) * WW * CC;

        #pragma unroll
        for (int t = 0; t < 8; ++t) {
            const int owl = owp + t * 8;        // local 0..63
            const int ow  = hw * 64 + owl;
            int je, jo;
            if (par) { je = (ow + 1) >> 1; jo = (ow - 1) >> 1; }
            else     { je = ow >> 1;       jo = (ow >> 1) - 1; }
            const bool vje = (unsigned)je < WW;
            const bool vjo = (unsigned)jo < WW;

            float acc[8];
            #pragma unroll
            for (int e = 0; e < 8; ++e) acc[e] = 0.f;

            if (va0) {
                if (vje) tap(acc, w[0][0], Xr0 + je * CC + c0);
                if (vjo) tap(acc, w[0][1], Xr0 + jo * CC + c0);
            }
            if (va1) {
                if (vje) tap(acc, w[1][0], Xr1 + je * CC + c0);
                if (vjo) tap(acc, w[1][1], Xr1 + jo * CC + c0);
            }

            union { unsigned u[4]; bf16x8 v; } pk;
            pk.u[0] = cvtpk(acc[0], acc[1]);
            pk.u[1] = cvtpk(acc[2], acc[3]);
            pk.u[2] = cvtpk(acc[4], acc[5]);
            pk.u[3] = cvtpk(acc[6], acc[7]);
            tbuf[pb][owl * 32 + (cg ^ (owl & 7))] = pk.v;
        }
    };

    // consume tile g from tbuf[cb]: D[f][ow] = pwt * t
    auto consume = [&](int g, int cb) {
        const int hw = g & 1;
        const int oh = (g >> 1) & (OH - 1);
        const int b  = g >> 8;

        f32x4 acc[4][4];
        #pragma unroll
        for (int mi = 0; mi < 4; ++mi)
            #pragma unroll
            for (int ni = 0; ni < 4; ++ni)
                acc[mi][ni] = (f32x4){0.f, 0.f, 0.f, 0.f};

        #pragma unroll
        for (int kk = 0; kk < 8; ++kk) {
            const int kg = kk * 4 + lk8;
            bf16x8 af[4], bfr[4];
            #pragma unroll
            for (int mi = 0; mi < 4; ++mi) {
                const int owl = mi * 16 + lr;
                af[mi] = tbuf[cb][owl * 32 + (kg ^ (owl & 7))];
            }
            #pragma unroll
            for (int ni = 0; ni < 4; ++ni)
                bfr[ni] = pwt_v[(cw * 64 + ni * 16 + lr) * 32 + kg];
            #pragma unroll
            for (int mi = 0; mi < 4; ++mi)
                #pragma unroll
                for (int ni = 0; ni < 4; ++ni)
                    acc[mi][ni] = __builtin_amdgcn_mfma_f32_16x16x32_bf16(
                        bfr[ni], af[mi], acc[mi][ni], 0, 0, 0);
        }

        float* obase = out + ((size_t)(b * OH + oh) * OW + hw * 64) * FF;
        #pragma unroll
        for (int ni = 0; ni < 4; ++ni) {
            const int f0 = cw * 64 + ni * 16 + lk8 * 4;
            #pragma unroll
            for (int mi = 0; mi < 4; ++mi) {
                const int ow = mi * 16 + lr;
                f32x4 v = acc[mi][ni] + bv[ni];
                v[0] = v[0] > 0.f ? v[0] : 0.f;
                v[1] = v[1] > 0.f ? v[1] : 0.f;
                v[2] = v[2] > 0.f ? v[2] : 0.f;
                v[3] = v[3] > 0.f ? v[3] : 0.f;
                __builtin_nontemporal_store(v, reinterpret_cast<f32x4*>(&obase[(size_t)ow * FF + f0]));
            }
        }
    };

    // ---------------- pipeline ----------------
    if (producer) produce(g0, 0);
    __syncthreads();
    for (int it = 0; it < TPB; ++it) {
        if (producer) {
            if (it + 1 < TPB) produce(g0 + it + 1, (it + 1) & 1);
        } else {
            consume(g0 + it, it & 1);
        }
        __syncthreads();
    }
}

extern "C" void kernel_launch(void* const* d_in, const int* in_sizes, int n_in,
                              void* d_out, int out_size, void* d_ws, size_t ws_size,
                              hipStream_t stream) {
    (void)in_sizes; (void)n_in; (void)out_size; (void)ws_size;
    const float* X    = (const float*)d_in[0];
    const float* dw   = (const float*)d_in[1];
    const float* pw   = (const float*)d_in[2];
    const float* bias = (const float*)d_in[3];
    float* out = (float*)d_out;
    short* pwt = (short*)d_ws;                        // 256*256*2 = 128 KiB
    float* dwb = (float*)((char*)d_ws + 131072);      // 4*256*4*4 = 16 KiB

    prep_kernel<<<dim3(257), dim3(256), 0, stream>>>(pw, dw, pwt, dwb);
    sepconvt_kernel<<<dim3(BB * OH * 2 / TPB), dim3(512), 0, stream>>>(X, dwb, pwt, bias, out);
}